// Round 7
// baseline (383.320 us; speedup 1.0000x reference)
//
#include <hip/hip_runtime.h>
#include <hip/hip_bf16.h>

// MHA fwd: B=4,S=2048,D=1024,H=16,DK=DV=64, causal.
// v8b: resubmit of v8 (R6 bench was an infra container failure, no verdict —
// same signature as R2, which passed on unchanged resubmit).
// v8: pipeline the projection GEMMs (same medicine that fixed attn_k in v5).
//  * qkv_gemm: weight LDS double-buffered (glds) + T14 act prefetch: issue
//    next-tile fp32 loads to REGS at iter start, pkbf+ds_write AFTER compute
//    (latency hides under 32 MFMAs).  One barrier per K-tile.  64KB LDS.
//  * gemm_bb: attn_k-style dbuf prefetch (both sides glds), 64KB LDS.
//  * attn_k / transpose_w4 / XCD-locality decode unchanged.

typedef __attribute__((ext_vector_type(8))) __bf16 bf16x8;
typedef __attribute__((ext_vector_type(8))) unsigned short ushort8v;
typedef __attribute__((ext_vector_type(4))) unsigned short ushort4v;
typedef __attribute__((ext_vector_type(4))) unsigned uint4v;
typedef __attribute__((ext_vector_type(2))) unsigned uint2v;
typedef __attribute__((ext_vector_type(4))) float float4v;

#define MFMA16(a, b, c) __builtin_amdgcn_mfma_f32_16x16x32_bf16((a), (b), (c), 0, 0, 0)
#define GLDS16(g, l)                                                     \
    __builtin_amdgcn_global_load_lds(                                    \
        (const __attribute__((address_space(1))) void*)(g),              \
        (__attribute__((address_space(3))) void*)(l), 16, 0, 0)

__device__ __forceinline__ unsigned short f2bf(float f) {   // RNE
    union { float f; unsigned u; } v; v.f = f;
    unsigned r = v.u + 0x7fffu + ((v.u >> 16) & 1u);
    return (unsigned short)(r >> 16);
}
__device__ __forceinline__ unsigned pkbf(float a, float b) { // 2xf32 -> 2xbf16
    union { float f; unsigned u; } x, y; x.f = a; y.f = b;
    return __builtin_amdgcn_perm(y.u + 0x8000u, x.u + 0x8000u, 0x07060302u);
}
__device__ __forceinline__ float exp2_fast(float x) {
#if __has_builtin(__builtin_amdgcn_exp2f)
    return __builtin_amdgcn_exp2f(x);
#else
    return __builtin_exp2f(x);
#endif
}

// ---------------------------------------------------------------------------
// 4x W [K=1024][N=1024] fp32 -> Wt [N][K] bf16 (scale folded), one launch
__global__ __launch_bounds__(256) void transpose_w4(
    const float* __restrict__ W0, const float* __restrict__ W1,
    const float* __restrict__ W2, const float* __restrict__ W3,
    unsigned short* __restrict__ T0, unsigned short* __restrict__ T1,
    unsigned short* __restrict__ T2, unsigned short* __restrict__ T3)
{
    __shared__ unsigned short T[64][72];
    const int z = blockIdx.z;
    const float* W = z == 0 ? W0 : z == 1 ? W1 : z == 2 ? W2 : W3;
    unsigned short* Wt = z == 0 ? T0 : z == 1 ? T1 : z == 2 ? T2 : T3;
    const float scale = (z == 1) ? 0.125f * 1.44269504088896f : 1.0f; // K: softmax*log2e
    const int t = threadIdx.x;
    const int n0 = blockIdx.x * 64, k0 = blockIdx.y * 64;
    for (int i = 0; i < 4; i++) {
        int idx = i * 256 + t, r = idx >> 4, c = (idx & 15) * 4;
        float4v v = *(const float4v*)&W[(size_t)(k0 + r) * 1024 + n0 + c];
        T[c + 0][r] = f2bf(v.x * scale); T[c + 1][r] = f2bf(v.y * scale);
        T[c + 2][r] = f2bf(v.z * scale); T[c + 3][r] = f2bf(v.w * scale);
    }
    __syncthreads();
    for (int i = 0; i < 4; i++) {
        int idx = i * 256 + t, r = idx >> 4, c = (idx & 15) * 4;
        ushort4v o; o.x = T[r][c]; o.y = T[r][c + 1]; o.z = T[r][c + 2]; o.w = T[r][c + 3];
        *(ushort4v*)&Wt[(size_t)(n0 + r) * 1024 + k0 + c] = o;
    }
}

// ---------------------------------------------------------------------------
// Grouped QKV projection, 1536 blocks of 128x128, BK=64, K=1024.
// XCD-locality decode as v7 (activation-panel blocks co-XCD, FETCH verified
// 74MB).  v8: weight tile double-buffered via glds; activation prefetched to
// registers at iter start (8 fp32 dwordx4 issues, no waits), converted and
// ds_written AFTER the MFMA block so the HBM latency hides under compute.
// One __syncthreads per K-tile.
// ---------------------------------------------------------------------------
__global__ __launch_bounds__(256) void qkv_gemm(
    const float* __restrict__ Aq, const float* __restrict__ Ak,
    const float* __restrict__ Av,
    const unsigned short* __restrict__ WQt, const unsigned short* __restrict__ WKt,
    const unsigned short* __restrict__ WVt,
    unsigned short* __restrict__ Qb, unsigned short* __restrict__ Kb,
    unsigned short* __restrict__ Vto)
{
    __shared__ __align__(16) unsigned short wtS[2][128 * 64];
    __shared__ __align__(16) unsigned short actS[2][128 * 64];

    const int t = threadIdx.x;
    const int lane = t & 63, w = t >> 6;
    const int lanelo = lane & 15, quad = lane >> 4;
    const int wm = w >> 1, wn = w & 1;

    const int d = blockIdx.x;
    const int xcd = d & 7;
    const int s = d >> 3;                  // 0..191
    const int group = s >> 6;              // 0,1,2
    const int u = s & 63;
    const bool vsw = (group == 2);

    const float* act; const unsigned short* wt; unsigned short* out;
    if (group == 0)      { act = Aq; wt = WQt; out = Qb; }
    else if (group == 1) { act = Ak; wt = WKt; out = Kb; }
    else                 { act = Av; wt = WVt; out = Vto; }

    const int big = (((u >> 3) << 3) | xcd) * 128;   // activation-panel tile
    const int sml = (u & 7) * 128;                   // other-operand tile
    int m0, n0, ldc;
    if (!vsw) { m0 = big; n0 = sml; ldc = 1024; }
    else      { n0 = big; m0 = sml; ldc = 8192; }
    const int act0 = vsw ? n0 : m0;      // activation tile row base
    const int wt0  = vsw ? m0 : n0;      // weight tile row base

    float4v ar[4][2];                    // prefetched fp32 act tile (32 regs)

    auto wt_stage = [&](int buf, int k0) {
        for (int i = 0; i < 4; i++) {
            int idx = i * 256 + t, row = idx >> 3, ch = idx & 7;
            GLDS16(wt + (size_t)(wt0 + row) * 1024 + k0 + ch * 8, &wtS[buf][idx * 8]);
        }
    };
    auto act_load = [&](int k0) {        // issue only, no waits
        for (int i = 0; i < 4; i++) {
            int si = i * 256 + t, row = si >> 3, ch = si & 7;
            const float* ap = act + (size_t)(act0 + row) * 1024 + k0 + ch * 8;
            ar[i][0] = *(const float4v*)ap;
            ar[i][1] = *(const float4v*)(ap + 4);
        }
    };
    auto act_write = [&](int buf) {      // waits loads here (after compute)
        for (int i = 0; i < 4; i++) {
            int si = i * 256 + t;
            uint4v o4 = { pkbf(ar[i][0].x, ar[i][0].y), pkbf(ar[i][0].z, ar[i][0].w),
                          pkbf(ar[i][1].x, ar[i][1].y), pkbf(ar[i][1].z, ar[i][1].w) };
            *(uint4v*)&actS[buf][si * 8] = o4;
        }
    };

    float4v acc[4][4];
    for (int i = 0; i < 4; i++)
        for (int j = 0; j < 4; j++) acc[i][j] = (float4v)(0.f);

    // prologue: tile 0
    wt_stage(0, 0);
    act_load(0);
    act_write(0);
    __syncthreads();

    for (int tt = 0; tt < 16; ++tt) {
        const int cur = tt & 1;
        if (tt < 15) {
            wt_stage(cur ^ 1, (tt + 1) * 64);   // async -> LDS buf^1
            act_load((tt + 1) * 64);            // async -> regs
        }
        const unsigned short* As_ = vsw ? &wtS[cur][0] : &actS[cur][0];
        const unsigned short* Bs_ = vsw ? &actS[cur][0] : &wtS[cur][0];
        for (int ks = 0; ks < 2; ks++) {
            bf16x8 af[4], bfr[4];
            for (int mi = 0; mi < 4; mi++)
                af[mi] = *(const bf16x8*)&As_[(wm * 64 + mi * 16 + lanelo) * 64 + ks * 32 + quad * 8];
            for (int ni = 0; ni < 4; ni++)
                bfr[ni] = *(const bf16x8*)&Bs_[(wn * 64 + ni * 16 + lanelo) * 64 + ks * 32 + quad * 8];
            for (int mi = 0; mi < 4; mi++)
                for (int ni = 0; ni < 4; ni++)
                    acc[mi][ni] = MFMA16(af[mi], bfr[ni], acc[mi][ni]);
        }
        if (tt < 15) act_write(cur ^ 1);        // fp32 latency hid under MFMAs
        __syncthreads();                         // drains glds + ds_writes
    }

    for (int mi = 0; mi < 4; mi++)
        for (int ni = 0; ni < 4; ni++) {
            int col = n0 + wn * 64 + ni * 16 + lanelo;
            for (int rr = 0; rr < 4; rr++) {
                int row = m0 + wm * 64 + mi * 16 + quad * 4 + rr;
                out[(size_t)row * ldc + col] = f2bf(acc[mi][ni][rr]);
            }
        }
}

// ---------------------------------------------------------------------------
// O-projection: C[8192,1024] fp32 = A[8192,1024]bf16 @ Bt[1024,1024]bf16^T.
// 512 blocks, XCD-locality decode.  v8: dbuf + prefetch-before-compute
// (attn_k's verified pattern), one barrier per K-tile.
// ---------------------------------------------------------------------------
__global__ __launch_bounds__(256) void gemm_bb(
    const unsigned short* __restrict__ A, const unsigned short* __restrict__ Bt,
    float* __restrict__ Cp, int M, int N, int K)
{
    __shared__ __align__(16) unsigned short As[2][128 * 64];
    __shared__ __align__(16) unsigned short Bs[2][128 * 64];

    const int t = threadIdx.x;
    const int lane = t & 63, w = t >> 6;
    const int lanelo = lane & 15, quad = lane >> 4;
    const int wm = w >> 1, wn = w & 1;

    const int d = blockIdx.x;
    const int xcd = d & 7, s = d >> 3;               // s: 0..63
    const int m0 = ((((s >> 3) << 3) | xcd)) * 128;  // 64 m-tiles, panel->XCD
    const int n0 = (s & 7) * 128;                    // 8 n-tiles

    auto stage = [&](int buf, int k0) {
        for (int i = 0; i < 4; i++) {
            int idx = i * 256 + t, row = idx >> 3, ch = idx & 7;
            GLDS16(A + (size_t)(m0 + row) * K + k0 + ch * 8, &As[buf][idx * 8]);
        }
        for (int i = 0; i < 4; i++) {
            int idx = i * 256 + t, row = idx >> 3, ch = idx & 7;
            GLDS16(Bt + (size_t)(n0 + row) * K + k0 + ch * 8, &Bs[buf][idx * 8]);
        }
    };

    float4v acc[4][4];
    for (int i = 0; i < 4; i++)
        for (int j = 0; j < 4; j++) acc[i][j] = (float4v)(0.f);

    const int NT = K >> 6;
    stage(0, 0);
    __syncthreads();

    for (int tt = 0; tt < NT; ++tt) {
        const int cur = tt & 1;
        if (tt + 1 < NT) stage(cur ^ 1, (tt + 1) * 64);
        for (int ks = 0; ks < 2; ks++) {
            bf16x8 af[4], bfr[4];
            for (int mi = 0; mi < 4; mi++)
                af[mi] = *(const bf16x8*)&As[cur][(wm * 64 + mi * 16 + lanelo) * 64 + ks * 32 + quad * 8];
            for (int ni = 0; ni < 4; ni++)
                bfr[ni] = *(const bf16x8*)&Bs[cur][(wn * 64 + ni * 16 + lanelo) * 64 + ks * 32 + quad * 8];
            for (int mi = 0; mi < 4; mi++)
                for (int ni = 0; ni < 4; ni++)
                    acc[mi][ni] = MFMA16(af[mi], bfr[ni], acc[mi][ni]);
        }
        __syncthreads();
    }

    for (int mi = 0; mi < 4; mi++)
        for (int ni = 0; ni < 4; ni++) {
            int col = n0 + wn * 64 + ni * 16 + lanelo;
            for (int r = 0; r < 4; r++) {
                int row = m0 + wm * 64 + mi * 16 + quad * 4 + r;
                Cp[(size_t)row * N + col] = acc[mi][ni][r];
            }
        }
}

// ---------------------------------------------------------------------------
// Flash causal attention — unchanged from v5 (verified 74 us).
// ---------------------------------------------------------------------------
__global__ __launch_bounds__(256, 4) void attn_k(
    const unsigned short* __restrict__ Qb, const unsigned short* __restrict__ Kb,
    const unsigned short* __restrict__ Vt, unsigned short* __restrict__ Ob)
{
    __shared__ __align__(16) unsigned short Ks[2][64 * 64];
    __shared__ __align__(16) unsigned short Vs[2][64 * 64];
    __shared__ __align__(16) unsigned short Ps[4][16 * 64];

    const int t = threadIdx.x;
    const int lane = t & 63, w = t >> 6;
    const int lanelo = lane & 15, quad = lane >> 4;
    const int bh = blockIdx.x;                  // same (b,h) -> same XCD
    const int b = bh >> 4, h = bh & 15;

    unsigned short* pw = &Ps[w][0];
    const int rsw = (lanelo & 7) * 8;           // K/V read XOR (elems)
    const int l7 = lanelo & 7;                  // Ps chunk XOR key

    auto stage = [&](int buf, int kt) {
        for (int i = 0; i < 2; i++) {
            int idx = i * 256 + t, row = idx >> 3, ch = idx & 7;
            GLDS16(Kb + ((size_t)(b * 2048 + kt * 64 + row)) * 1024 + h * 64
                       + ((ch ^ (row & 7)) << 3),
                   &Ks[buf][idx * 8]);
        }
        for (int i = 0; i < 2; i++) {
            int idx = i * 256 + t, row = idx >> 3, ch = idx & 7;
            GLDS16(Vt + (size_t)(h * 64 + row) * 8192 + b * 2048 + kt * 64
                       + ((ch ^ (row & 7)) << 3),
                   &Vs[buf][idx * 8]);
        }
    };

    for (int half = 0; half < 2; half++) {
        const int qt = half ? blockIdx.y : 31 - blockIdx.y;
        const int qb = qt * 64;
        const int nkt = qt + 1;
        const int q = qb + w * 16 + lanelo;

        bf16x8 qf[2];
        {
            const unsigned short* qp = Qb + ((size_t)(b * 2048) + q) * 1024 + h * 64 + quad * 8;
            qf[0] = *(const bf16x8*)(qp);
            qf[1] = *(const bf16x8*)(qp + 32);
        }
        float4v o[4];
        for (int i = 0; i < 4; i++) o[i] = (float4v)(0.f);
        float m_ = -__builtin_inff(), l_ = 0.f;

        stage(0, 0);
        __syncthreads();

        int cur = 0;
        for (int kt = 0; kt < nkt; kt++) {
            if (kt + 1 < nkt) stage(cur ^ 1, kt + 1);   // prefetch next tile

            const unsigned short* ks = &Ks[cur][0];
            const unsigned short* vs = &Vs[cur][0];

            // S^T tiles: A = K rows (m=key), B = Q rows (n=q)
            float4v sc[4];
            for (int nt = 0; nt < 4; nt++) {
                sc[nt] = (float4v)(0.f);
                for (int c = 0; c < 2; c++) {
                    bf16x8 kf = *(const bf16x8*)
                        &ks[(nt * 16 + lanelo) * 64 + ((c * 32 + quad * 8) ^ rsw)];
                    sc[nt] = MFMA16(kf, qf[c], sc[nt]);
                }
            }
            if (kt == nkt - 1) {                        // only diagonal needs mask
                const int kb0 = qb + quad * 4;
                for (int nt = 0; nt < 4; nt++)
                    for (int r = 0; r < 4; r++)
                        if (kb0 + nt * 16 + r > q) sc[nt][r] = -__builtin_inff();
            }
            float mx = sc[0][0];
            for (int nt = 0; nt < 4; nt++)
                for (int r = 0; r < 4; r++) mx = fmaxf(mx, sc[nt][r]);
            mx = fmaxf(mx, __shfl_xor(mx, 16, 64));
            mx = fmaxf(mx, __shfl_xor(mx, 32, 64));
            if (!__all(mx <= m_ + 8.f)) {               // defer-max (T13), log2 dom
                float mnew = fmaxf(m_, mx);
                float alpha = exp2_fast(m_ - mnew);
                l_ *= alpha;
                for (int vt = 0; vt < 4; vt++)
                    for (int r = 0; r < 4; r++) o[vt][r] *= alpha;
                m_ = mnew;
            }
            float rs = 0.f;
            for (int nt = 0; nt < 4; nt++)
                for (int r = 0; r < 4; r++) {
                    float e = exp2_fast(sc[nt][r] - m_);
                    sc[nt][r] = e; rs += e;
                }
            rs += __shfl_xor(rs, 16, 64);
            rs += __shfl_xor(rs, 32, 64);
            l_ += rs;

            // P^T -> Ps (swizzled 16B chunks), b64 writes
            for (int nt = 0; nt < 4; nt++) {
                uint2v pv;
                pv.x = pkbf(sc[nt][0], sc[nt][1]);
                pv.y = pkbf(sc[nt][2], sc[nt][3]);
                *(uint2v*)((char*)pw + lanelo * 128
                           + ((((nt << 1) | (quad >> 1)) ^ l7) << 4)
                           + ((quad & 1) << 3)) = pv;
            }
            asm volatile("s_waitcnt lgkmcnt(0)" ::: "memory");
            __builtin_amdgcn_sched_barrier(0);
            // O^T += V^T P^T : A = V^T (m=dv), B = P (n=q)
            for (int c = 0; c < 2; c++) {
                bf16x8 pf = *(const bf16x8*)((const char*)pw + lanelo * 128
                                             + (((c * 4 + quad) ^ l7) << 4));
                for (int vt = 0; vt < 4; vt++) {
                    bf16x8 vf = *(const bf16x8*)
                        &vs[(vt * 16 + lanelo) * 64 + ((c * 32 + quad * 8) ^ rsw)];
                    o[vt] = MFMA16(vf, pf, o[vt]);
                }
            }
            __syncthreads();                            // prefetch landed by now
            cur ^= 1;
        }

        // epilogue: normalize, transpose O^T -> O via swizzled Ps, 16B stores
        float inv = 1.0f / l_;
        for (int vt = 0; vt < 4; vt++) {
            uint2v ov;
            ov.x = pkbf(o[vt][0] * inv, o[vt][1] * inv);
            ov.y = pkbf(o[vt][2] * inv, o[vt][3] * inv);
            *(uint2v*)((char*)pw + lanelo * 128
                       + ((((vt << 1) | (quad >> 1)) ^ l7) << 4)
                       + ((quad & 1) << 3)) = ov;
        }
        asm volatile("s_waitcnt lgkmcnt(0)" ::: "memory");
        __builtin_amdgcn_sched_barrier(0);
        for (int i = 0; i < 2; i++) {
            int qr = i * 8 + (lane >> 3);
            int ch = lane & 7;
            ushort8v ov = *(const ushort8v*)((const char*)pw + qr * 128
                                             + ((ch ^ (qr & 7)) << 4));
            *(ushort8v*)(Ob + ((size_t)(b * 2048) + qb + w * 16 + qr) * 1024
                         + h * 64 + ch * 8) = ov;
        }
    }
}

// ---------------------------------------------------------------------------
extern "C" void kernel_launch(void* const* d_in, const int* in_sizes, int n_in,
                              void* d_out, int out_size, void* d_ws, size_t ws_size,
                              hipStream_t stream) {
    const float* queries = (const float*)d_in[0];
    const float* keys    = (const float*)d_in[1];
    const float* values  = (const float*)d_in[2];
    // d_in[3] = causal mask, handled analytically
    const float* W_Q = (const float*)d_in[4];
    const float* W_K = (const float*)d_in[5];
    const float* W_V = (const float*)d_in[6];
    const float* W_O = (const float*)d_in[7];

    const size_t SZ = (size_t)4 * 2048 * 1024;        // 8.4M elems
    const size_t WSZ = (size_t)1024 * 1024;
    unsigned short* Qb  = (unsigned short*)d_ws;
    unsigned short* Kb  = Qb + SZ;
    unsigned short* Vt  = Kb + SZ;                    // [1024][8192]
    unsigned short* Ab  = Vt + SZ;                    // attn output
    unsigned short* WQt = Ab + SZ;
    unsigned short* WKt = WQt + WSZ;
    unsigned short* WVt = WKt + WSZ;
    unsigned short* WOt = WVt + WSZ;                  // ~75.5 MB total

    dim3 blk(256);
    hipLaunchKernelGGL(transpose_w4, dim3(16, 16, 4), blk, 0, stream,
                       W_Q, W_K, W_V, W_O, WQt, WKt, WVt, WOt);

    hipLaunchKernelGGL(qkv_gemm, dim3(1536), blk, 0, stream,
                       queries, keys, values, WQt, WKt, WVt, Qb, Kb, Vt);

    hipLaunchKernelGGL(attn_k, dim3(64, 16), blk, 0, stream, Qb, Kb, Vt, Ab);

    hipLaunchKernelGGL(gemm_bb, dim3(512), blk, 0, stream,
                       Ab, WOt, (float*)d_out, 8192, 1024, 1024);
}

// Round 8
// 314.874 us; speedup vs baseline: 1.2174x; 1.2174x over previous
//
#include <hip/hip_runtime.h>
#include <hip/hip_bf16.h>

// MHA fwd: B=4,S=2048,D=1024,H=16,DK=DV=64, causal.
// v9: v7 structure (v8's explicit dbuf REGRESSED 127->175us: act reg-waits
// drain the ordered vmcnt queue incl. next-tile weight glds + 64KB LDS halves
// residency — reverted) + XOR bank-swizzle on the GEMM LDS tiles.
//  v7 counters: qkv SQ_LDS_BANK_CONFLICT=1.9e7 = ~31us/CU of LDS-pipe
//  serialization in a 127us dispatch.  Fragment reads have row-stride 128B
//  -> 16 lanes/quad hit one 16B bank slot = 16-way conflict (5.69x, m136).
//  Fix = the same (row&7) 16B-chunk XOR proven on attn_k (v4, +18%):
//  glds source pre-swizzled, reg-staged act ds_write swizzled, reads XOR'd.

typedef __attribute__((ext_vector_type(8))) __bf16 bf16x8;
typedef __attribute__((ext_vector_type(8))) unsigned short ushort8v;
typedef __attribute__((ext_vector_type(4))) unsigned short ushort4v;
typedef __attribute__((ext_vector_type(4))) unsigned uint4v;
typedef __attribute__((ext_vector_type(2))) unsigned uint2v;
typedef __attribute__((ext_vector_type(4))) float float4v;

#define MFMA16(a, b, c) __builtin_amdgcn_mfma_f32_16x16x32_bf16((a), (b), (c), 0, 0, 0)
#define GLDS16(g, l)                                                     \
    __builtin_amdgcn_global_load_lds(                                    \
        (const __attribute__((address_space(1))) void*)(g),              \
        (__attribute__((address_space(3))) void*)(l), 16, 0, 0)

__device__ __forceinline__ unsigned short f2bf(float f) {   // RNE
    union { float f; unsigned u; } v; v.f = f;
    unsigned r = v.u + 0x7fffu + ((v.u >> 16) & 1u);
    return (unsigned short)(r >> 16);
}
__device__ __forceinline__ unsigned pkbf(float a, float b) { // 2xf32 -> 2xbf16
    union { float f; unsigned u; } x, y; x.f = a; y.f = b;
    return __builtin_amdgcn_perm(y.u + 0x8000u, x.u + 0x8000u, 0x07060302u);
}
__device__ __forceinline__ float exp2_fast(float x) {
#if __has_builtin(__builtin_amdgcn_exp2f)
    return __builtin_amdgcn_exp2f(x);
#else
    return __builtin_exp2f(x);
#endif
}

// ---------------------------------------------------------------------------
// 4x W [K=1024][N=1024] fp32 -> Wt [N][K] bf16 (scale folded), one launch
__global__ __launch_bounds__(256) void transpose_w4(
    const float* __restrict__ W0, const float* __restrict__ W1,
    const float* __restrict__ W2, const float* __restrict__ W3,
    unsigned short* __restrict__ T0, unsigned short* __restrict__ T1,
    unsigned short* __restrict__ T2, unsigned short* __restrict__ T3)
{
    __shared__ unsigned short T[64][72];
    const int z = blockIdx.z;
    const float* W = z == 0 ? W0 : z == 1 ? W1 : z == 2 ? W2 : W3;
    unsigned short* Wt = z == 0 ? T0 : z == 1 ? T1 : z == 2 ? T2 : T3;
    const float scale = (z == 1) ? 0.125f * 1.44269504088896f : 1.0f; // K: softmax*log2e
    const int t = threadIdx.x;
    const int n0 = blockIdx.x * 64, k0 = blockIdx.y * 64;
    for (int i = 0; i < 4; i++) {
        int idx = i * 256 + t, r = idx >> 4, c = (idx & 15) * 4;
        float4v v = *(const float4v*)&W[(size_t)(k0 + r) * 1024 + n0 + c];
        T[c + 0][r] = f2bf(v.x * scale); T[c + 1][r] = f2bf(v.y * scale);
        T[c + 2][r] = f2bf(v.z * scale); T[c + 3][r] = f2bf(v.w * scale);
    }
    __syncthreads();
    for (int i = 0; i < 4; i++) {
        int idx = i * 256 + t, r = idx >> 4, c = (idx & 15) * 4;
        ushort4v o; o.x = T[r][c]; o.y = T[r][c + 1]; o.z = T[r][c + 2]; o.w = T[r][c + 3];
        *(ushort4v*)&Wt[(size_t)(n0 + r) * 1024 + k0 + c] = o;
    }
}

// ---------------------------------------------------------------------------
// Grouped QKV projection, 1536 blocks of 128x128, BK=64, K=1024 (v7 decode).
// LDS tiles XOR-swizzled at 16B-chunk granularity by (row&7).
// ---------------------------------------------------------------------------
__global__ __launch_bounds__(256) void qkv_gemm(
    const float* __restrict__ Aq, const float* __restrict__ Ak,
    const float* __restrict__ Av,
    const unsigned short* __restrict__ WQt, const unsigned short* __restrict__ WKt,
    const unsigned short* __restrict__ WVt,
    unsigned short* __restrict__ Qb, unsigned short* __restrict__ Kb,
    unsigned short* __restrict__ Vto)
{
    __shared__ __align__(16) unsigned short As[128 * 64];
    __shared__ __align__(16) unsigned short Bs[128 * 64];

    const int t = threadIdx.x;
    const int lane = t & 63, w = t >> 6;
    const int lanelo = lane & 15, quad = lane >> 4;
    const int wm = w >> 1, wn = w & 1;
    const int rsw = (lanelo & 7) << 3;     // read-side XOR (elements)

    const int d = blockIdx.x;
    const int xcd = d & 7;
    const int s = d >> 3;                  // 0..191
    const int group = s >> 6;              // 0,1,2
    const int u = s & 63;
    const bool vsw = (group == 2);

    const float* act; const unsigned short* wt; unsigned short* out;
    if (group == 0)      { act = Aq; wt = WQt; out = Qb; }
    else if (group == 1) { act = Ak; wt = WKt; out = Kb; }
    else                 { act = Av; wt = WVt; out = Vto; }

    const int big = (((u >> 3) << 3) | xcd) * 128;   // activation-panel tile
    const int sml = (u & 7) * 128;                   // other-operand tile
    int m0, n0, ldc;
    if (!vsw) { m0 = big; n0 = sml; ldc = 1024; }
    else      { n0 = big; m0 = sml; ldc = 8192; }
    const int act0 = vsw ? n0 : m0;      // activation tile row base
    const int wt0  = vsw ? m0 : n0;      // weight tile row base
    unsigned short* actS = vsw ? Bs : As;
    unsigned short* wtS  = vsw ? As : Bs;

    float4v acc[4][4];
    for (int i = 0; i < 4; i++)
        for (int j = 0; j < 4; j++) acc[i][j] = (float4v)(0.f);

    for (int k0 = 0; k0 < 1024; k0 += 64) {
        // weight tile via async glds, source pre-swizzled (linear LDS dest)
        for (int i = 0; i < 4; i++) {
            int idx = i * 256 + t, row = idx >> 3, ch = idx & 7;
            GLDS16(wt + (size_t)(wt0 + row) * 1024 + k0 + ((ch ^ (row & 7)) << 3),
                   &wtS[idx * 8]);
        }
        // activation tile: fp32 -> bf16 reg-staged, ds_write to swizzled slot
        for (int i = 0; i < 4; i++) {
            int si = i * 256 + t, row = si >> 3, ch = si & 7;
            const float* ap = act + (size_t)(act0 + row) * 1024 + k0 + ch * 8;
            float4v x = *(const float4v*)ap;
            float4v y = *(const float4v*)(ap + 4);
            uint4v o4 = { pkbf(x.x, x.y), pkbf(x.z, x.w),
                          pkbf(y.x, y.y), pkbf(y.z, y.w) };
            *(uint4v*)&actS[row * 64 + ((ch ^ (row & 7)) << 3)] = o4;
        }
        __syncthreads();
        for (int ks = 0; ks < 2; ks++) {
            bf16x8 af[4], bfr[4];
            for (int mi = 0; mi < 4; mi++)
                af[mi] = *(const bf16x8*)
                    &As[(wm * 64 + mi * 16 + lanelo) * 64 + ((ks * 32 + quad * 8) ^ rsw)];
            for (int ni = 0; ni < 4; ni++)
                bfr[ni] = *(const bf16x8*)
                    &Bs[(wn * 64 + ni * 16 + lanelo) * 64 + ((ks * 32 + quad * 8) ^ rsw)];
            for (int mi = 0; mi < 4; mi++)
                for (int ni = 0; ni < 4; ni++)
                    acc[mi][ni] = MFMA16(af[mi], bfr[ni], acc[mi][ni]);
        }
        __syncthreads();
    }

    for (int mi = 0; mi < 4; mi++)
        for (int ni = 0; ni < 4; ni++) {
            int col = n0 + wn * 64 + ni * 16 + lanelo;
            for (int rr = 0; rr < 4; rr++) {
                int row = m0 + wm * 64 + mi * 16 + quad * 4 + rr;
                out[(size_t)row * ldc + col] = f2bf(acc[mi][ni][rr]);
            }
        }
}

// ---------------------------------------------------------------------------
// O-projection: C[8192,1024] fp32 = A[8192,1024]bf16 @ Bt[1024,1024]bf16^T.
// 512 blocks, XCD-locality decode (v7).  LDS tiles XOR-swizzled.
// ---------------------------------------------------------------------------
__global__ __launch_bounds__(256) void gemm_bb(
    const unsigned short* __restrict__ A, const unsigned short* __restrict__ Bt,
    float* __restrict__ Cp, int M, int N, int K)
{
    __shared__ __align__(16) unsigned short As[128 * 64];
    __shared__ __align__(16) unsigned short Bs[128 * 64];

    const int t = threadIdx.x;
    const int lane = t & 63, w = t >> 6;
    const int lanelo = lane & 15, quad = lane >> 4;
    const int wm = w >> 1, wn = w & 1;
    const int rsw = (lanelo & 7) << 3;

    const int d = blockIdx.x;
    const int xcd = d & 7, s = d >> 3;               // s: 0..63
    const int m0 = ((((s >> 3) << 3) | xcd)) * 128;  // 64 m-tiles, panel->XCD
    const int n0 = (s & 7) * 128;                    // 8 n-tiles

    float4v acc[4][4];
    for (int i = 0; i < 4; i++)
        for (int j = 0; j < 4; j++) acc[i][j] = (float4v)(0.f);

    for (int k0 = 0; k0 < K; k0 += 64) {
        for (int i = 0; i < 4; i++) {
            int idx = i * 256 + t, row = idx >> 3, ch = idx & 7;
            GLDS16(A + (size_t)(m0 + row) * K + k0 + ((ch ^ (row & 7)) << 3),
                   &As[idx * 8]);
        }
        for (int i = 0; i < 4; i++) {
            int idx = i * 256 + t, row = idx >> 3, ch = idx & 7;
            GLDS16(Bt + (size_t)(n0 + row) * K + k0 + ((ch ^ (row & 7)) << 3),
                   &Bs[idx * 8]);
        }
        __syncthreads();
        for (int ks = 0; ks < 2; ks++) {
            bf16x8 af[4], bfr[4];
            for (int mi = 0; mi < 4; mi++)
                af[mi] = *(const bf16x8*)
                    &As[(wm * 64 + mi * 16 + lanelo) * 64 + ((ks * 32 + quad * 8) ^ rsw)];
            for (int ni = 0; ni < 4; ni++)
                bfr[ni] = *(const bf16x8*)
                    &Bs[(wn * 64 + ni * 16 + lanelo) * 64 + ((ks * 32 + quad * 8) ^ rsw)];
            for (int mi = 0; mi < 4; mi++)
                for (int ni = 0; ni < 4; ni++)
                    acc[mi][ni] = MFMA16(af[mi], bfr[ni], acc[mi][ni]);
        }
        __syncthreads();
    }

    for (int mi = 0; mi < 4; mi++)
        for (int ni = 0; ni < 4; ni++) {
            int col = n0 + wn * 64 + ni * 16 + lanelo;
            for (int r = 0; r < 4; r++) {
                int row = m0 + wm * 64 + mi * 16 + quad * 4 + r;
                Cp[(size_t)row * N + col] = acc[mi][ni][r];
            }
        }
}

// ---------------------------------------------------------------------------
// Flash causal attention — unchanged from v5 (verified 74 us).
// ---------------------------------------------------------------------------
__global__ __launch_bounds__(256, 4) void attn_k(
    const unsigned short* __restrict__ Qb, const unsigned short* __restrict__ Kb,
    const unsigned short* __restrict__ Vt, unsigned short* __restrict__ Ob)
{
    __shared__ __align__(16) unsigned short Ks[2][64 * 64];
    __shared__ __align__(16) unsigned short Vs[2][64 * 64];
    __shared__ __align__(16) unsigned short Ps[4][16 * 64];

    const int t = threadIdx.x;
    const int lane = t & 63, w = t >> 6;
    const int lanelo = lane & 15, quad = lane >> 4;
    const int bh = blockIdx.x;                  // same (b,h) -> same XCD
    const int b = bh >> 4, h = bh & 15;

    unsigned short* pw = &Ps[w][0];
    const int rsw = (lanelo & 7) * 8;           // K/V read XOR (elems)
    const int l7 = lanelo & 7;                  // Ps chunk XOR key

    auto stage = [&](int buf, int kt) {
        for (int i = 0; i < 2; i++) {
            int idx = i * 256 + t, row = idx >> 3, ch = idx & 7;
            GLDS16(Kb + ((size_t)(b * 2048 + kt * 64 + row)) * 1024 + h * 64
                       + ((ch ^ (row & 7)) << 3),
                   &Ks[buf][idx * 8]);
        }
        for (int i = 0; i < 2; i++) {
            int idx = i * 256 + t, row = idx >> 3, ch = idx & 7;
            GLDS16(Vt + (size_t)(h * 64 + row) * 8192 + b * 2048 + kt * 64
                       + ((ch ^ (row & 7)) << 3),
                   &Vs[buf][idx * 8]);
        }
    };

    for (int half = 0; half < 2; half++) {
        const int qt = half ? blockIdx.y : 31 - blockIdx.y;
        const int qb = qt * 64;
        const int nkt = qt + 1;
        const int q = qb + w * 16 + lanelo;

        bf16x8 qf[2];
        {
            const unsigned short* qp = Qb + ((size_t)(b * 2048) + q) * 1024 + h * 64 + quad * 8;
            qf[0] = *(const bf16x8*)(qp);
            qf[1] = *(const bf16x8*)(qp + 32);
        }
        float4v o[4];
        for (int i = 0; i < 4; i++) o[i] = (float4v)(0.f);
        float m_ = -__builtin_inff(), l_ = 0.f;

        stage(0, 0);
        __syncthreads();

        int cur = 0;
        for (int kt = 0; kt < nkt; kt++) {
            if (kt + 1 < nkt) stage(cur ^ 1, kt + 1);   // prefetch next tile

            const unsigned short* ks = &Ks[cur][0];
            const unsigned short* vs = &Vs[cur][0];

            // S^T tiles: A = K rows (m=key), B = Q rows (n=q)
            float4v sc[4];
            for (int nt = 0; nt < 4; nt++) {
                sc[nt] = (float4v)(0.f);
                for (int c = 0; c < 2; c++) {
                    bf16x8 kf = *(const bf16x8*)
                        &ks[(nt * 16 + lanelo) * 64 + ((c * 32 + quad * 8) ^ rsw)];
                    sc[nt] = MFMA16(kf, qf[c], sc[nt]);
                }
            }
            if (kt == nkt - 1) {                        // only diagonal needs mask
                const int kb0 = qb + quad * 4;
                for (int nt = 0; nt < 4; nt++)
                    for (int r = 0; r < 4; r++)
                        if (kb0 + nt * 16 + r > q) sc[nt][r] = -__builtin_inff();
            }
            float mx = sc[0][0];
            for (int nt = 0; nt < 4; nt++)
                for (int r = 0; r < 4; r++) mx = fmaxf(mx, sc[nt][r]);
            mx = fmaxf(mx, __shfl_xor(mx, 16, 64));
            mx = fmaxf(mx, __shfl_xor(mx, 32, 64));
            if (!__all(mx <= m_ + 8.f)) {               // defer-max (T13), log2 dom
                float mnew = fmaxf(m_, mx);
                float alpha = exp2_fast(m_ - mnew);
                l_ *= alpha;
                for (int vt = 0; vt < 4; vt++)
                    for (int r = 0; r < 4; r++) o[vt][r] *= alpha;
                m_ = mnew;
            }
            float rs = 0.f;
            for (int nt = 0; nt < 4; nt++)
                for (int r = 0; r < 4; r++) {
                    float e = exp2_fast(sc[nt][r] - m_);
                    sc[nt][r] = e; rs += e;
                }
            rs += __shfl_xor(rs, 16, 64);
            rs += __shfl_xor(rs, 32, 64);
            l_ += rs;

            // P^T -> Ps (swizzled 16B chunks), b64 writes
            for (int nt = 0; nt < 4; nt++) {
                uint2v pv;
                pv.x = pkbf(sc[nt][0], sc[nt][1]);
                pv.y = pkbf(sc[nt][2], sc[nt][3]);
                *(uint2v*)((char*)pw + lanelo * 128
                           + ((((nt << 1) | (quad >> 1)) ^ l7) << 4)
                           + ((quad & 1) << 3)) = pv;
            }
            asm volatile("s_waitcnt lgkmcnt(0)" ::: "memory");
            __builtin_amdgcn_sched_barrier(0);
            // O^T += V^T P^T : A = V^T (m=dv), B = P (n=q)
            for (int c = 0; c < 2; c++) {
                bf16x8 pf = *(const bf16x8*)((const char*)pw + lanelo * 128
                                             + (((c * 4 + quad) ^ l7) << 4));
                for (int vt = 0; vt < 4; vt++) {
                    bf16x8 vf = *(const bf16x8*)
                        &vs[(vt * 16 + lanelo) * 64 + ((c * 32 + quad * 8) ^ rsw)];
                    o[vt] = MFMA16(vf, pf, o[vt]);
                }
            }
            __syncthreads();                            // prefetch landed by now
            cur ^= 1;
        }

        // epilogue: normalize, transpose O^T -> O via swizzled Ps, 16B stores
        float inv = 1.0f / l_;
        for (int vt = 0; vt < 4; vt++) {
            uint2v ov;
            ov.x = pkbf(o[vt][0] * inv, o[vt][1] * inv);
            ov.y = pkbf(o[vt][2] * inv, o[vt][3] * inv);
            *(uint2v*)((char*)pw + lanelo * 128
                       + ((((vt << 1) | (quad >> 1)) ^ l7) << 4)
                       + ((quad & 1) << 3)) = ov;
        }
        asm volatile("s_waitcnt lgkmcnt(0)" ::: "memory");
        __builtin_amdgcn_sched_barrier(0);
        for (int i = 0; i < 2; i++) {
            int qr = i * 8 + (lane >> 3);
            int ch = lane & 7;
            ushort8v ov = *(const ushort8v*)((const char*)pw + qr * 128
                                             + ((ch ^ (qr & 7)) << 4));
            *(ushort8v*)(Ob + ((size_t)(b * 2048) + qb + w * 16 + qr) * 1024
                         + h * 64 + ch * 8) = ov;
        }
    }
}

// ---------------------------------------------------------------------------
extern "C" void kernel_launch(void* const* d_in, const int* in_sizes, int n_in,
                              void* d_out, int out_size, void* d_ws, size_t ws_size,
                              hipStream_t stream) {
    const float* queries = (const float*)d_in[0];
    const float* keys    = (const float*)d_in[1];
    const float* values  = (const float*)d_in[2];
    // d_in[3] = causal mask, handled analytically
    const float* W_Q = (const float*)d_in[4];
    const float* W_K = (const float*)d_in[5];
    const float* W_V = (const float*)d_in[6];
    const float* W_O = (const float*)d_in[7];

    const size_t SZ = (size_t)4 * 2048 * 1024;        // 8.4M elems
    const size_t WSZ = (size_t)1024 * 1024;
    unsigned short* Qb  = (unsigned short*)d_ws;
    unsigned short* Kb  = Qb + SZ;
    unsigned short* Vt  = Kb + SZ;                    // [1024][8192]
    unsigned short* Ab  = Vt + SZ;                    // attn output
    unsigned short* WQt = Ab + SZ;
    unsigned short* WKt = WQt + WSZ;
    unsigned short* WVt = WKt + WSZ;
    unsigned short* WOt = WVt + WSZ;                  // ~75.5 MB total

    dim3 blk(256);
    hipLaunchKernelGGL(transpose_w4, dim3(16, 16, 4), blk, 0, stream,
                       W_Q, W_K, W_V, W_O, WQt, WKt, WVt, WOt);

    hipLaunchKernelGGL(qkv_gemm, dim3(1536), blk, 0, stream,
                       queries, keys, values, WQt, WKt, WVt, Qb, Kb, Vt);

    hipLaunchKernelGGL(attn_k, dim3(64, 16), blk, 0, stream, Qb, Kb, Vt, Ab);

    hipLaunchKernelGGL(gemm_bb, dim3(512), blk, 0, stream,
                       Ab, WOt, (float*)d_out, 8192, 1024, 1024);
}